// Round 1
// baseline (180.327 us; speedup 1.0000x reference)
//
#include <hip/hip_runtime.h>
#include <math.h>

// Problem constants
#define BZ      64
#define NC      2048
#define HH      14
#define HW      196        // 14*14
#define NCLS    1000
#define SPLITS  8
#define CPB     (NC/SPLITS)   // 256 channels per block
#define CHUNK   8
#define NCHUNK  (CPB/CHUNK)   // 32
#define LPAD    200           // padded channel stride in LDS (floats); 200%32=8
#define NTRI    105           // 14*15/2 upper-triangle entries of G

// ws layout (floats) — unchanged from previous version
#define CAM_OFF  0                                  // [64][8][3][196]
#define G_OFF    (BZ*SPLITS*3*HW)                   // 301056, [64][8][196] (only first 105 used)
#define S_OFF    (G_OFF + BZ*SPLITS*HW)             // 401408, [64][8][14]
#define TERM_OFF (S_OFF + BZ*SPLITS*HH)             // 408576, [64]

// ---------------------------------------------------------------------------
// Kernel 1: per (batch, channel-split).
//   Waves 0-1 (t<112): Gram via per-thread column outer products.
//     thread (cL=t&7, jc=t>>3) reads column jc of channel cL's 14x14 tile
//     (14 x ds_read_b32, 2-way bank alias only) and does 105 FMAs into a
//     register triangle acc[105]. Each LDS element is read exactly once.
//   Wave 2 (128<=t<177): CAM partials (float4 over 196 positions) + row sums.
//   All 192 threads stage chunks global->reg->LDS (double-buffered).
// ---------------------------------------------------------------------------
__global__ __launch_bounds__(192) void k_stage1(
    const float* __restrict__ F, const float* __restrict__ W,
    const int* __restrict__ idx, float* __restrict__ ws)
{
  __shared__ __align__(16) float Fs[2][CHUNK*LPAD];   // 2 x 1600 floats (12.8 KB)
  __shared__ __align__(16) float wls[3][CPB];         // 3 KB
  __shared__ __align__(16) float sred[HW];            // 0.78 KB
  __shared__ __align__(16) float gacc[112*NTRI];      // 47 KB

  const int t = threadIdx.x;
  const int s = blockIdx.x;     // split
  const int b = blockIdx.y;     // batch
  const int cbase = s*CPB;

  const int i0 = idx[b*3+0], i1 = idx[b*3+1], i2 = idx[b*3+2];
  for (int i = t; i < CPB; i += 192){
    wls[0][i] = W[(size_t)i0*NC + cbase + i];
    wls[1][i] = W[(size_t)i1*NC + cbase + i];
    wls[2][i] = W[(size_t)i2*NC + cbase + i];
  }

  const float* Fb = F + ((size_t)b*NC + cbase)*HW;

  const bool isG   = (t < 112);
  const int  cL    = t & 7;        // channel-in-chunk (fast) -> conflict-free cols
  const int  jc    = t >> 3;       // column 0..13
  const bool isCam = (t >= 128 && t < 177);
  const int  cp    = t - 128;      // cam position group (4 positions each)

  float acc[NTRI];
  #pragma unroll
  for (int k=0;k<NTRI;k++) acc[k]=0.f;
  float4 c0a = make_float4(0.f,0.f,0.f,0.f);
  float4 c1a = make_float4(0.f,0.f,0.f,0.f);
  float4 c2a = make_float4(0.f,0.f,0.f,0.f);
  float4 sA  = make_float4(0.f,0.f,0.f,0.f);

  // staging regs: 392 float4 per chunk over 192 threads
  float4 p0, p1, p2;
  auto loadChunk = [&](int ch){
    const float4* src = (const float4*)(Fb + (size_t)ch*CHUNK*HW);
    p0 = src[t];
    p1 = src[t+192];
    if (t < 8) p2 = src[t+384];
  };
  auto storeChunk = [&](int bufi){
    float4* dst = (float4*)(&Fs[bufi][0]);
    int i = t;       dst[(i/49)*(LPAD/4) + (i%49)] = p0;
    i = t + 192;     dst[(i/49)*(LPAD/4) + (i%49)] = p1;
    if (t < 8){ i = t + 384; dst[(i/49)*(LPAD/4) + (i%49)] = p2; }
  };

  loadChunk(0);
  storeChunk(0);
  __syncthreads();

  #pragma unroll 1
  for (int ch = 0; ch < NCHUNK; ++ch){
    const int bufi = ch & 1;
    if (ch+1 < NCHUNK) loadChunk(ch+1);   // prefetch next slab into regs
    const float* Fsb = &Fs[bufi][0];

    if (isG){
      const float* colp = Fsb + cL*LPAD + jc;
      float x[14];
      #pragma unroll
      for (int m=0;m<14;m++) x[m] = colp[m*HH];
      #pragma unroll
      for (int m=0;m<14;m++){
        #pragma unroll
        for (int n=m;n<14;n++){
          acc[14*m - (m*(m-1))/2 + (n-m)] += x[m]*x[n];
        }
      }
    }
    if (isCam){
      float w0a[CHUNK], w1a[CHUNK], w2a[CHUNK];
      *(float4*)&w0a[0] = *(const float4*)&wls[0][ch*CHUNK];
      *(float4*)&w0a[4] = *(const float4*)&wls[0][ch*CHUNK+4];
      *(float4*)&w1a[0] = *(const float4*)&wls[1][ch*CHUNK];
      *(float4*)&w1a[4] = *(const float4*)&wls[1][ch*CHUNK+4];
      *(float4*)&w2a[0] = *(const float4*)&wls[2][ch*CHUNK];
      *(float4*)&w2a[4] = *(const float4*)&wls[2][ch*CHUNK+4];
      #pragma unroll
      for (int c=0;c<CHUNK;c++){
        float4 v = *(const float4*)(Fsb + c*LPAD + 4*cp);
        c0a.x += w0a[c]*v.x; c0a.y += w0a[c]*v.y; c0a.z += w0a[c]*v.z; c0a.w += w0a[c]*v.w;
        c1a.x += w1a[c]*v.x; c1a.y += w1a[c]*v.y; c1a.z += w1a[c]*v.z; c1a.w += w1a[c]*v.w;
        c2a.x += w2a[c]*v.x; c2a.y += w2a[c]*v.y; c2a.z += w2a[c]*v.z; c2a.w += w2a[c]*v.w;
        sA.x += v.x; sA.y += v.y; sA.z += v.z; sA.w += v.w;
      }
    }
    if (ch+1 < NCHUNK) storeChunk((ch+1)&1);  // other buffer, reads of it synced last iter
    __syncthreads();
  }

  // ---- epilogue ----
  const size_t pslot = (size_t)(b*SPLITS + s);
  if (isCam){
    float* base = ws + CAM_OFF + pslot*3*HW;
    *(float4*)(base          + 4*cp) = c0a;
    *(float4*)(base + HW     + 4*cp) = c1a;
    *(float4*)(base + 2*HW   + 4*cp) = c2a;
    *(float4*)(sred + 4*cp) = sA;
  }
  if (isG){
    float* gr = &gacc[t*NTRI];   // stride 105 (odd) -> 2-way alias on writes
    #pragma unroll
    for (int k=0;k<NTRI;k++) gr[k] = acc[k];
  }
  __syncthreads();

  if (t < NTRI){
    float a = 0.f;
    for (int th=0; th<112; th++) a += gacc[th*NTRI + t];  // lanes consecutive -> conflict-free
    ws[G_OFF + pslot*HW + t] = a;
  }
  if (t >= 128 && t < 128+HH){
    int r = t - 128;
    float a = 0.f;
    #pragma unroll
    for (int j=0;j<HH;j++) a += sred[r*HH+j];
    ws[S_OFF + pslot*HH + r] = a;
  }
}

// ---------------------------------------------------------------------------
// block reduce: MODE 0=sum, 1=min, 2=max; result broadcast to all 256 threads
// ---------------------------------------------------------------------------
template<int MODE>
__device__ __forceinline__ float bred(float v, float* red){
  #pragma unroll
  for (int o=32;o>0;o>>=1){
    float u = __shfl_down(v, o, 64);
    if (MODE==0) v += u; else if (MODE==1) v = fminf(v,u); else v = fmaxf(v,u);
  }
  __syncthreads();
  if ((threadIdx.x & 63)==0) red[threadIdx.x>>6] = v;
  __syncthreads();
  float r = red[0];
  #pragma unroll
  for (int w=1;w<4;w++){
    float u = red[w];
    if (MODE==0) r += u; else if (MODE==1) r = fminf(r,u); else r = fmaxf(r,u);
  }
  return r;
}

// ---------------------------------------------------------------------------
// Kernel 2: per-batch — reduce partials, normalize cams, dst/ed1, quadratic
// forms for d01/d02, cross-entropy, per-batch term.  G now triangular (105).
// ---------------------------------------------------------------------------
__global__ __launch_bounds__(256) void k_stage2(
    const float* __restrict__ pred, const int* __restrict__ cla,
    const float* __restrict__ seg, float* __restrict__ ws)
{
  const int t = threadIdx.x, b = blockIdx.x;
  __shared__ float cam[3][HW], Gt[NTRI], Sv[HH];
  __shared__ float D1[HW], D2[HW], EE[HW];
  __shared__ float rowv[HH], dc1[HH], dc2[HH];
  __shared__ float red[4];
  __shared__ float scal[6];

  // A: reduce split partials
  if (t < HW){
    for (int k=0;k<3;k++){
      float a=0.f;
      for (int s=0;s<SPLITS;s++)
        a += ws[CAM_OFF + ((size_t)(b*SPLITS+s)*3 + k)*HW + t];
      cam[k][t]=a;
    }
  }
  if (t < NTRI){
    float g=0.f;
    for (int s=0;s<SPLITS;s++) g += ws[G_OFF + (size_t)(b*SPLITS+s)*HW + t];
    Gt[t]=g;
  }
  if (t < HH){
    float a=0.f;
    for (int s=0;s<SPLITS;s++) a += ws[S_OFF + (size_t)(b*SPLITS+s)*HH + t];
    Sv[t]=a;
  }
  __syncthreads();

  // B: per-cam min/max
  for (int k=0;k<3;k++){
    float v = (t<HW)? cam[k][t] : 3.0e38f;
    float mn = bred<1>(v, red);
    v = (t<HW)? cam[k][t] : -3.0e38f;
    float mx = bred<2>(v, red);
    if (t==0){ scal[2*k]=mn; scal[2*k+1]=mx; }
  }
  __syncthreads();

  // C: normalize (matches ref: (x-mn)/max(x-mn) * 255), dst, D, EE
  if (t < HW){
    float c0 = (cam[0][t]-scal[0]) / (scal[1]-scal[0]) * 255.0f;
    float c1 = (cam[1][t]-scal[2]) / (scal[3]-scal[2]) * 255.0f;
    float c2 = (cam[2][t]-scal[4]) / (scal[5]-scal[4]) * 255.0f;
    float dst = (c0 > 125.0f) ? 1.0f : 0.0f;
    D1[t] = c0 - c1; D2[t] = c0 - c2;
    float e = dst - seg[(size_t)b*HW + t] + 1e-6f;
    EE[t] = e*e;
  }
  __syncthreads();

  if (t < HH){
    float rs=0.f, d1=0.f, d2=0.f;
    #pragma unroll
    for (int j=0;j<HH;j++){
      rs += EE[t*HH+j];
      d1 += D1[j*HH+t];       // column sums of D
      d2 += D2[j*HH+t];
    }
    rowv[t] = sqrtf(rs); dc1[t]=d1; dc2[t]=d2;
  }
  __syncthreads();

  // D: H[m,m'] * G[m,m'] summed (G expanded from triangle by symmetry)
  float v1=0.f, v2=0.f;
  if (t < HW){
    int m = t/HH, mp = t%HH;
    float h1=0.f, h2=0.f;
    #pragma unroll
    for (int i=0;i<HH;i++){
      h1 += D1[i*HH+m]*D1[i*HH+mp];
      h2 += D2[i*HH+m]*D2[i*HH+mp];
    }
    int mm = (m<mp)?m:mp, nn = (m<mp)?mp:m;
    float g = Gt[14*mm - (mm*(mm-1))/2 + (nn-mm)];
    v1 = h1*g; v2 = h2*g;
  }
  float sx2_1 = bred<0>(v1, red);
  float sx2_2 = bred<0>(v2, red);

  // E: logsumexp cross-entropy
  const float* pb = pred + (size_t)b*NCLS;
  float mv = -3.0e38f;
  for (int i=t;i<NCLS;i+=256) mv = fmaxf(mv, pb[i]);
  mv = bred<2>(mv, red);
  float es = 0.f;
  for (int i=t;i<NCLS;i+=256) es += expf(pb[i]-mv);
  es = bred<0>(es, red);

  if (t==0){
    float lse = mv + logf(es);
    float ce  = lse - pb[cla[b]];
    float ed1 = 0.f;
    #pragma unroll
    for (int i=0;i<HH;i++) ed1 += rowv[i];
    ed1 *= (1.0f/14.0f);
    float sx1=0.f, sx2=0.f;
    #pragma unroll
    for (int m=0;m<HH;m++){ sx1 += dc1[m]*Sv[m]; sx2 += dc2[m]*Sv[m]; }
    const float NEPS2 = 401408.0f * 1e-12f;
    float d01 = sqrtf(sx2_1 + 2e-6f*sx1 + NEPS2) * (1.0f/2048.0f);
    float d02 = sqrtf(sx2_2 + 2e-6f*sx2 + NEPS2) * (1.0f/2048.0f);
    float term = ed1 + fmaxf(0.0f, 70.0f - d01 - d02) + ce;
    ws[TERM_OFF + b] = term;
  }
}

// ---------------------------------------------------------------------------
// Kernel 3: mean over 64 batch terms -> scalar
// ---------------------------------------------------------------------------
__global__ void k_stage3(const float* __restrict__ ws, float* __restrict__ out){
  float v = ws[TERM_OFF + threadIdx.x];
  #pragma unroll
  for (int o=32;o>0;o>>=1) v += __shfl_down(v, o, 64);
  if (threadIdx.x==0) out[0] = v * (1.0f/64.0f);
}

extern "C" void kernel_launch(void* const* d_in, const int* in_sizes, int n_in,
                              void* d_out, int out_size, void* d_ws, size_t ws_size,
                              hipStream_t stream) {
  const float* pred = (const float*)d_in[0];
  const int*   cla  = (const int*)  d_in[1];
  const float* seg  = (const float*)d_in[2];
  const float* F    = (const float*)d_in[3];
  const float* W    = (const float*)d_in[4];
  const int*   idx  = (const int*)  d_in[5];
  float* out = (float*)d_out;
  float* ws  = (float*)d_ws;

  dim3 g1(SPLITS, BZ);
  k_stage1<<<g1, 192, 0, stream>>>(F, W, idx, ws);
  k_stage2<<<BZ, 256, 0, stream>>>(pred, cla, seg, ws);
  k_stage3<<<1, 64, 0, stream>>>(ws, out);
}